// Round 1
// baseline (46.146 us; speedup 1.0000x reference)
//
#include <hip/hip_runtime.h>

// Problem constants (from reference setup_inputs)
constexpr int B    = 2;
constexpr int CIN  = 64;
constexpr int N    = 128;
constexpr int T    = 24;
constexpr int HID  = 64;
constexpr int COUT = 64;
constexpr int NT   = N * T;        // 3072
constexpr int ROWS = B * N * T;    // 6144

// ---------------------------------------------------------------------------
// Kernel A: per-row MLP.
//   For each row (b, n, t):
//     h[k]  = b1[k] + sum_c x[b,c,n,t] * W1[c,k]
//     mv[c] = sum_k h[k] * W2[k,c]          -> store mv + b2  (mvb2)
//     mh[c] = sum_k h[k] * W2[HID+k,c]      -> store mh
//   Stored in [b][t][n][c] layout so kernel B reads contiguous panels.
// 4 rows per block, 64 lanes per row.
// ---------------------------------------------------------------------------
__global__ __launch_bounds__(256) void k_mlp(
    const float* __restrict__ x,
    const float* __restrict__ W1,
    const float* __restrict__ b1,
    const float* __restrict__ W2,
    const float* __restrict__ b2,
    float* __restrict__ mvb2,
    float* __restrict__ mh)
{
    __shared__ float xs[4][64];
    __shared__ float hs[4][64];

    const int r   = threadIdx.x >> 6;   // row within block (0..3)
    const int k   = threadIdx.x & 63;   // lane = channel index
    const int row = blockIdx.x * 4 + r; // flat row = b*NT + n*T + t

    const int b  = row / NT;
    const int nt = row - b * NT;        // n*T + t

    // x[b][c][n][t]
    xs[r][k] = x[(size_t)b * CIN * NT + (size_t)k * NT + nt];
    __syncthreads();

    float h = b1[k];
#pragma unroll
    for (int c = 0; c < CIN; ++c) {
        h += xs[r][c] * W1[c * HID + k];
    }
    hs[r][k] = h;
    __syncthreads();

    float mv = 0.f, mhv = 0.f;
#pragma unroll
    for (int q = 0; q < HID; ++q) {
        const float hq = hs[r][q];
        mv  += hq * W2[q * COUT + k];
        mhv += hq * W2[(HID + q) * COUT + k];
    }

    const int n = nt / T;
    const int t = nt - n * T;
    const int o = ((b * T + t) * N + n) * COUT + k;  // [b][t][n][c]
    mvb2[o] = mv + b2[k];
    mh[o]   = mhv;
}

// ---------------------------------------------------------------------------
// Kernel B: attention aggregation + bias term + output transpose.
//   For each (b, t): upd[i,c] = (sum_j A[i,j]) * mvb2[i,c] + sum_j A[i,j]*mh[j,c]
//   where A[i,j] = attention[b,0,i,j,t].
//   Output: out[b][c][i][t].
// Grid: (B*T) * 4 blocks; each block handles 32 i-rows.
// 4 waves/block, each wave owns 8 i-rows; lane = channel c.
// ---------------------------------------------------------------------------
__global__ __launch_bounds__(256) void k_att(
    const float* __restrict__ att,
    const float* __restrict__ mvb2,
    const float* __restrict__ mh,
    float* __restrict__ out)
{
    __shared__ float mhs[128][64];   // mh panel for this (b,t): 32 KB

    const int blk   = blockIdx.x;
    const int itile = blk & 3;
    const int bt    = blk >> 2;            // b*T + t
    const int b     = bt / T;
    const int t     = bt - b * T;
    const int tid   = threadIdx.x;

    // Stage mh[b][t][:][:] (8192 floats) into LDS, coalesced float4.
    const float4* src = (const float4*)(mh + (size_t)bt * N * COUT);
    float4*       dst = (float4*)(&mhs[0][0]);
#pragma unroll
    for (int u = 0; u < 8; ++u) {
        dst[tid + 256 * u] = src[tid + 256 * u];
    }
    __syncthreads();

    const int w = tid >> 6;   // wave 0..3
    const int c = tid & 63;   // channel

    // attention[b][i][j][t]: base + i*N*T + j*T + t
    const float* abase = att + (size_t)b * N * N * T + t;

#pragma unroll
    for (int r8 = 0; r8 < 8; ++r8) {
        const int i = itile * 32 + w * 8 + r8;
        const float* arow = abase + (size_t)i * N * T;

        float acc = 0.f;
        float s   = 0.f;
#pragma unroll 8
        for (int j = 0; j < N; ++j) {
            const float a = arow[(size_t)j * T];  // wave-uniform broadcast load
            s   += a;
            acc += a * mhs[j][c];
        }

        const float u = s * mvb2[((size_t)bt * N + i) * COUT + c] + acc;
        out[(((size_t)b * COUT + c) * N + i) * T + t] = u;
    }
}

// ---------------------------------------------------------------------------
extern "C" void kernel_launch(void* const* d_in, const int* in_sizes, int n_in,
                              void* d_out, int out_size, void* d_ws, size_t ws_size,
                              hipStream_t stream)
{
    const float* x   = (const float*)d_in[0];
    const float* att = (const float*)d_in[1];
    const float* W1  = (const float*)d_in[2];
    const float* b1  = (const float*)d_in[3];
    const float* W2  = (const float*)d_in[4];
    const float* b2  = (const float*)d_in[5];
    float* out = (float*)d_out;

    float* mvb2 = (float*)d_ws;                 // ROWS*COUT floats
    float* mhws = mvb2 + (size_t)ROWS * COUT;   // ROWS*COUT floats

    k_mlp<<<ROWS / 4, 256, 0, stream>>>(x, W1, b1, W2, b2, mvb2, mhws);
    k_att<<<B * T * 4, 256, 0, stream>>>(att, mvb2, mhws, out);
}

// Round 2
// 31.804 us; speedup vs baseline: 1.4509x; 1.4509x over previous
//
#include <hip/hip_runtime.h>

// Problem constants (from reference setup_inputs)
constexpr int B    = 2;
constexpr int CIN  = 64;
constexpr int N    = 128;
constexpr int T    = 24;
constexpr int HID  = 64;
constexpr int COUT = 64;
constexpr int NT   = N * T;        // 3072
constexpr int ROWS = B * N * T;    // 6144

// ---------------------------------------------------------------------------
// Kernel A: per-row MLP (unchanged from R1; ~2-3 us, not the bottleneck).
//   h = x_row @ W1 + b1 ; mv = h @ W2[:HID] ; mh = h @ W2[HID:]
//   Stored [b][t][n][c] so kernel B reads contiguous panels.
// ---------------------------------------------------------------------------
__global__ __launch_bounds__(256) void k_mlp(
    const float* __restrict__ x,
    const float* __restrict__ W1,
    const float* __restrict__ b1,
    const float* __restrict__ W2,
    const float* __restrict__ b2,
    float* __restrict__ mvb2,
    float* __restrict__ mh)
{
    __shared__ float xs[4][64];
    __shared__ float hs[4][64];

    const int r   = threadIdx.x >> 6;
    const int k   = threadIdx.x & 63;
    const int row = blockIdx.x * 4 + r;

    const int b  = row / NT;
    const int nt = row - b * NT;

    xs[r][k] = x[(size_t)b * CIN * NT + (size_t)k * NT + nt];
    __syncthreads();

    float h = b1[k];
#pragma unroll
    for (int c = 0; c < CIN; ++c) {
        h += xs[r][c] * W1[c * HID + k];
    }
    hs[r][k] = h;
    __syncthreads();

    float mv = 0.f, mhv = 0.f;
#pragma unroll
    for (int q = 0; q < HID; ++q) {
        const float hq = hs[r][q];
        mv  += hq * W2[q * COUT + k];
        mhv += hq * W2[(HID + q) * COUT + k];
    }

    const int n = nt / T;
    const int t = nt - n * T;
    const int o = ((b * T + t) * N + n) * COUT + k;
    mvb2[o] = mv + b2[k];
    mh[o]   = mhv;
}

// ---------------------------------------------------------------------------
// Kernel B v2: attention aggregation, restructured for occupancy + ILP.
//   Grid: (B*T) * 8 blocks; each block owns 16 i-rows of one (b,t) matmul
//   C[i,c] = asum_i * mvb2[i,c] + sum_j A[i,j] * mh[j,c].
//   4 waves/block; each wave processes its 4 i-rows JOINTLY in one j-loop:
//   one LDS read of mhs[j][c] feeds 4 FMAs; 4 independent wave-uniform att
//   loads per j (unroll 8 -> 32 loads in flight) hide L2 latency.
// ---------------------------------------------------------------------------
__global__ __launch_bounds__(256) void k_att(
    const float* __restrict__ att,
    const float* __restrict__ mvb2,
    const float* __restrict__ mh,
    float* __restrict__ out)
{
    __shared__ float mhs[N][COUT];   // 32 KB panel for this (b,t)

    const int blk   = blockIdx.x;
    const int itile = blk & 7;            // 8 tiles of 16 i-rows
    const int bt    = blk >> 3;           // b*T + t
    const int b     = bt / T;
    const int t     = bt - b * T;
    const int tid   = threadIdx.x;

    // Stage mh[b][t][:][:] (8192 floats) into LDS, coalesced float4.
    const float4* src = (const float4*)(mh + (size_t)bt * N * COUT);
    float4*       dst = (float4*)(&mhs[0][0]);
#pragma unroll
    for (int u = 0; u < 8; ++u) {
        dst[tid + 256 * u] = src[tid + 256 * u];
    }
    __syncthreads();

    const int w = tid >> 6;   // wave 0..3
    const int c = tid & 63;   // channel (lane)
    const int ibase = itile * 16 + w * 4;

    // attention[b][i][j][t]
    const float* a0 = att + (size_t)b * N * NT + (size_t)(ibase + 0) * NT + t;
    const float* a1 = a0 + NT;
    const float* a2 = a1 + NT;
    const float* a3 = a2 + NT;

    float acc0 = 0.f, acc1 = 0.f, acc2 = 0.f, acc3 = 0.f;
    float s0 = 0.f, s1 = 0.f, s2 = 0.f, s3 = 0.f;

#pragma unroll 8
    for (int j = 0; j < N; ++j) {
        const float v  = mhs[j][c];
        const float x0 = a0[(size_t)j * T];   // wave-uniform broadcast loads
        const float x1 = a1[(size_t)j * T];
        const float x2 = a2[(size_t)j * T];
        const float x3 = a3[(size_t)j * T];
        s0 += x0; acc0 += x0 * v;
        s1 += x1; acc1 += x1 * v;
        s2 += x2; acc2 += x2 * v;
        s3 += x3; acc3 += x3 * v;
    }

    // Epilogue: upd = asum * (mv + b2) + acc ; out[b][c][i][t]
    const float* mb = mvb2 + ((size_t)bt * N + ibase) * COUT + c;
    float*       ob = out + ((size_t)b * COUT + c) * NT + (size_t)ibase * T + t;
    ob[0 * T] = s0 * mb[0 * COUT] + acc0;
    ob[1 * T] = s1 * mb[1 * COUT] + acc1;
    ob[2 * T] = s2 * mb[2 * COUT] + acc2;
    ob[3 * T] = s3 * mb[3 * COUT] + acc3;
}

// ---------------------------------------------------------------------------
extern "C" void kernel_launch(void* const* d_in, const int* in_sizes, int n_in,
                              void* d_out, int out_size, void* d_ws, size_t ws_size,
                              hipStream_t stream)
{
    const float* x   = (const float*)d_in[0];
    const float* att = (const float*)d_in[1];
    const float* W1  = (const float*)d_in[2];
    const float* b1  = (const float*)d_in[3];
    const float* W2  = (const float*)d_in[4];
    const float* b2  = (const float*)d_in[5];
    float* out = (float*)d_out;

    float* mvb2 = (float*)d_ws;
    float* mhws = mvb2 + (size_t)ROWS * COUT;

    k_mlp<<<ROWS / 4, 256, 0, stream>>>(x, W1, b1, W2, b2, mvb2, mhws);
    k_att<<<B * T * 8, 256, 0, stream>>>(att, mvb2, mhws, out);
}

// Round 3
// 29.471 us; speedup vs baseline: 1.5658x; 1.0792x over previous
//
#include <hip/hip_runtime.h>

// Problem constants (from reference setup_inputs)
constexpr int B    = 2;
constexpr int CIN  = 64;
constexpr int N    = 128;
constexpr int T    = 24;
constexpr int HID  = 64;
constexpr int COUT = 64;
constexpr int NT   = N * T;        // 3072
constexpr int ROWS = B * N * T;    // 6144

// ---------------------------------------------------------------------------
// Kernel A: per-row MLP (measured ~2.6 us; not the bottleneck).
//   h = x_row @ W1 + b1 ; mv = h @ W2[:HID] ; mh = h @ W2[HID:]
//   Stored [b][t][n][c] so kernel B reads contiguous panels.
// ---------------------------------------------------------------------------
__global__ __launch_bounds__(256) void k_mlp(
    const float* __restrict__ x,
    const float* __restrict__ W1,
    const float* __restrict__ b1,
    const float* __restrict__ W2,
    const float* __restrict__ b2,
    float* __restrict__ mvb2,
    float* __restrict__ mh)
{
    __shared__ float xs[4][64];
    __shared__ float hs[4][64];

    const int r   = threadIdx.x >> 6;
    const int k   = threadIdx.x & 63;
    const int row = blockIdx.x * 4 + r;

    const int b  = row / NT;
    const int nt = row - b * NT;

    xs[r][k] = x[(size_t)b * CIN * NT + (size_t)k * NT + nt];
    __syncthreads();

    float h = b1[k];
#pragma unroll
    for (int c = 0; c < CIN; ++c) {
        h += xs[r][c] * W1[c * HID + k];
    }
    hs[r][k] = h;
    __syncthreads();

    float mv = 0.f, mhv = 0.f;
#pragma unroll
    for (int q = 0; q < HID; ++q) {
        const float hq = hs[r][q];
        mv  += hq * W2[q * COUT + k];
        mhv += hq * W2[(HID + q) * COUT + k];
    }

    const int n = nt / T;
    const int t = nt - n * T;
    const int o = ((b * T + t) * N + n) * COUT + k;
    mvb2[o] = mv + b2[k];
    mh[o]   = mhv;
}

// ---------------------------------------------------------------------------
// Kernel B v3: attention aggregation with LDS-staged att tile.
//   Block = (bt, itile of 16 i-rows). Phase 0 cooperatively gathers
//   as[16][128] = att[b, ibase+r, j, t] (8 independent scattered loads per
//   thread, fully pipelined — kills the R2 serial-L2-latency chain) and
//   mhs[128][64] = mh panel (coalesced float4). Phase 1 j-loop is pure LDS:
//   ds_read_b128 broadcast of 4 att values + 4 b32 mh reads + 32 VALU.
// ---------------------------------------------------------------------------
__global__ __launch_bounds__(256) void k_att(
    const float* __restrict__ att,
    const float* __restrict__ mvb2,
    const float* __restrict__ mh,
    float* __restrict__ out)
{
    __shared__ float mhs[N][COUT];   // 32 KB
    __shared__ float as_[16][N];     // 8 KB att tile

    const int blk   = blockIdx.x;
    const int itile = blk & 7;            // 8 tiles of 16 i-rows
    const int bt    = blk >> 3;           // b*T + t
    const int b     = bt / T;
    const int t     = bt - b * T;
    const int tid   = threadIdx.x;
    const int w     = tid >> 6;           // wave 0..3
    const int lane  = tid & 63;

    // --- Phase 0a: stage mh[b][t][:][:] (coalesced float4) ---
    const float4* src = (const float4*)(mh + (size_t)bt * N * COUT);
    float4*       dst = (float4*)(&mhs[0][0]);
#pragma unroll
    for (int u = 0; u < 8; ++u) {
        dst[tid + 256 * u] = src[tid + 256 * u];
    }

    // --- Phase 0b: gather att tile (independent scattered loads) ---
    // thread -> row r = w*4 + (lane>>4), columns j = (lane&15) + 16*u
    {
        const int r  = w * 4 + (lane >> 4);
        const int jl = lane & 15;
        const float* ab = att + ((size_t)b * N + (size_t)(itile * 16 + r)) * NT + t;
#pragma unroll
        for (int u = 0; u < 8; ++u) {
            const int j = jl + 16 * u;
            as_[r][j] = ab[(size_t)j * T];
        }
    }
    __syncthreads();

    // --- Phase 1: j-loop, pure LDS ---
    const int c  = lane;                // channel
    const int r0 = w * 4;               // this wave's 4 rows within tile

    float acc0 = 0.f, acc1 = 0.f, acc2 = 0.f, acc3 = 0.f;
    float s0 = 0.f, s1 = 0.f, s2 = 0.f, s3 = 0.f;

#pragma unroll 4
    for (int j = 0; j < N; j += 4) {
        const float4 a0 = *(const float4*)&as_[r0 + 0][j];
        const float4 a1 = *(const float4*)&as_[r0 + 1][j];
        const float4 a2 = *(const float4*)&as_[r0 + 2][j];
        const float4 a3 = *(const float4*)&as_[r0 + 3][j];
        const float m0 = mhs[j + 0][c];
        const float m1 = mhs[j + 1][c];
        const float m2 = mhs[j + 2][c];
        const float m3 = mhs[j + 3][c];

        acc0 += a0.x * m0 + a0.y * m1 + a0.z * m2 + a0.w * m3;
        acc1 += a1.x * m0 + a1.y * m1 + a1.z * m2 + a1.w * m3;
        acc2 += a2.x * m0 + a2.y * m1 + a2.z * m2 + a2.w * m3;
        acc3 += a3.x * m0 + a3.y * m1 + a3.z * m2 + a3.w * m3;
        s0 += a0.x + a0.y + a0.z + a0.w;
        s1 += a1.x + a1.y + a1.z + a1.w;
        s2 += a2.x + a2.y + a2.z + a2.w;
        s3 += a3.x + a3.y + a3.z + a3.w;
    }

    // --- Epilogue: upd = asum*(mv+b2) + acc ; out[b][c][i][t] ---
    const int ibase = itile * 16 + r0;
    const float* mb = mvb2 + ((size_t)bt * N + ibase) * COUT + c;
    float*       ob = out + ((size_t)b * COUT + c) * NT + (size_t)ibase * T + t;
    ob[0 * T] = s0 * mb[0 * COUT] + acc0;
    ob[1 * T] = s1 * mb[1 * COUT] + acc1;
    ob[2 * T] = s2 * mb[2 * COUT] + acc2;
    ob[3 * T] = s3 * mb[3 * COUT] + acc3;
}

// ---------------------------------------------------------------------------
extern "C" void kernel_launch(void* const* d_in, const int* in_sizes, int n_in,
                              void* d_out, int out_size, void* d_ws, size_t ws_size,
                              hipStream_t stream)
{
    const float* x   = (const float*)d_in[0];
    const float* att = (const float*)d_in[1];
    const float* W1  = (const float*)d_in[2];
    const float* b1  = (const float*)d_in[3];
    const float* W2  = (const float*)d_in[4];
    const float* b2  = (const float*)d_in[5];
    float* out = (float*)d_out;

    float* mvb2 = (float*)d_ws;
    float* mhws = mvb2 + (size_t)ROWS * COUT;

    k_mlp<<<ROWS / 4, 256, 0, stream>>>(x, W1, b1, W2, b2, mvb2, mhws);
    k_att<<<B * T * 8, 256, 0, stream>>>(att, mvb2, mhws, out);
}